// Round 14
// baseline (148.660 us; speedup 1.0000x reference)
//
#include <hip/hip_runtime.h>
#include <math.h>

// SpatialProcessor: 2-layer GAT over top-K cosine-sim graph. All f32.
// R13 -> R14: (a) sim output phase reverted to R12 rank-by-count (bitonic's
// 21-stage serial shfl chain regressed 68.6->74 at 28% occupancy). (b) sim
// and gemm1 are data-independent: fused into ONE fat kernel (626 sim blocks
// + 313 gemm1 blocks, 512 threads) so gemm1's FMA waves fill sim's latency
// stalls. pkeys un-aliased from h1p (both live concurrently now).

#define N_NODES 10000
#define EMB_D   16
#define IN_DIM  128
#define H1      4
#define CDIM    64
#define D1      256   // 4*64
#define K_TOP   20
#define NEIGH   21    // K_TOP + self loop
#define SROWS   32    // rows per sim block
#define NTILES  313   // ceil(10000/32) row-tiles
#define JSPLIT  2
#define HALFT   160   // j-tiles per half (padded 320/2)
#define CAPM    96    // candidate capacity per row (per half)
#define GUARD   0.016f // 2 * bf16 dot error bound (2^-7)
#define SIMB    (NTILES * JSPLIT)   // 626 sim blocks
#define G1B     313                 // gemm1 blocks (32 rows each)

typedef __attribute__((ext_vector_type(8)))  short short8;   // 8 bf16
typedef __attribute__((ext_vector_type(16))) float f32x16;

__device__ __forceinline__ unsigned monokey(float v) {
  unsigned u = __float_as_uint(v);
  return (u & 0x80000000u) ? ~u : (u | 0x80000000u);
}
__device__ __forceinline__ float invmono(unsigned m) {
  unsigned u = (m & 0x80000000u) ? (m ^ 0x80000000u) : ~m;
  return __uint_as_float(u);
}
__device__ __forceinline__ unsigned short f32_to_bf16(float f) {
  unsigned u = __float_as_uint(f);
  unsigned r = 0x7FFFu + ((u >> 16) & 1u);
  return (unsigned short)((u + r) >> 16);
}

// Fixed-order fmaf dot; MUST be bit-identical at every call site.
__device__ __forceinline__ float dot16q(float4 qa, float4 qb, float4 qc, float4 qd,
                                        float4 v0, float4 v1, float4 v2, float4 v3) {
  float a = 0.f;
  a = fmaf(qa.x, v0.x, a); a = fmaf(qa.y, v0.y, a);
  a = fmaf(qa.z, v0.z, a); a = fmaf(qa.w, v0.w, a);
  a = fmaf(qb.x, v1.x, a); a = fmaf(qb.y, v1.y, a);
  a = fmaf(qb.z, v1.z, a); a = fmaf(qb.w, v1.w, a);
  a = fmaf(qc.x, v2.x, a); a = fmaf(qc.y, v2.y, a);
  a = fmaf(qc.z, v2.z, a); a = fmaf(qc.w, v2.w, a);
  a = fmaf(qd.x, v3.x, a); a = fmaf(qd.y, v3.y, a);
  a = fmaf(qd.z, v3.z, a); a = fmaf(qd.w, v3.w, a);
  return a;
}

__global__ __launch_bounds__(256) void normalize_kernel(
    const float* __restrict__ emb, float* __restrict__ nrm,
    unsigned short* __restrict__ nrmh) {
  int i = blockIdx.x * 256 + threadIdx.x;
  if (i >= N_NODES) return;
  const float4* p = (const float4*)(emb + (size_t)i * EMB_D);
  float4 v[4];
  float ss = 0.f;
#pragma unroll
  for (int k = 0; k < 4; k++) {
    v[k] = p[k];
    ss = fmaf(v[k].x, v[k].x, ss);
    ss = fmaf(v[k].y, v[k].y, ss);
    ss = fmaf(v[k].z, v[k].z, ss);
    ss = fmaf(v[k].w, v[k].w, ss);
  }
  float nv = sqrtf(ss);
  float4* o = (float4*)(nrm + (size_t)i * EMB_D);
  ushort4* oh = (ushort4*)(nrmh + (size_t)i * EMB_D);
#pragma unroll
  for (int k = 0; k < 4; k++) {
    float4 t;
    t.x = v[k].x / nv; t.y = v[k].y / nv; t.z = v[k].z / nv; t.w = v[k].w / nv;
    o[k] = t;
    ushort4 h;
    h.x = f32_to_bf16(t.x); h.y = f32_to_bf16(t.y);
    h.z = f32_to_bf16(t.z); h.w = f32_to_bf16(t.w);
    oh[k] = h;
  }
}

// Fat kernel: blocks [0, SIMB) = sim_topk halves (R12 body, byte-identical);
// blocks [SIMB, SIMB+G1B) = gemm1 (32 rows, register-blocked 8x2, fused e1).
__global__ __launch_bounds__(512) void sim_gemm1_fused(
    const float* __restrict__ nrm, const unsigned short* __restrict__ nrmh,
    unsigned long long* __restrict__ pkeys,
    const float* __restrict__ A, const float* __restrict__ B,
    const float* __restrict__ a_src, const float* __restrict__ a_tgt,
    float* __restrict__ Cc, float* __restrict__ es, float* __restrict__ et) {
  __shared__ __align__(16) char smem[36096];
  int tid = threadIdx.x;
  int bid = blockIdx.x;

  if (bid < SIMB) {
    // ================= SIM BRANCH (R12 body) =================
    unsigned short* s_qbf = (unsigned short*)smem;                    // 1 KB
    float* s_qf = (float*)(smem + 1024);                              // 2 KB
    char* s_ovl = smem + 3072;                                        // 32 KB
    float (*s_smax)[256] = (float(*)[256])s_ovl;
    unsigned long long (*s_ckey)[CAPM] = (unsigned long long(*)[CAPM])s_ovl;
    unsigned short (*s_cid)[CAPM] = (unsigned short(*)[CAPM])(s_ovl + 24576);
    float* s_thr = (float*)(smem + 35840);                            // 128 B
    int* s_cnt = (int*)(smem + 35968);                                // 128 B

    int w = tid >> 6, lane = tid & 63;
    int lo5 = lane & 31, hi = lane >> 5;
    int row0 = (bid >> 1) * SROWS;
    int bh = bid & 1;
    int tbase = bh * HALFT;

    if (tid < SROWS * EMB_D) {
      int gi = row0 * EMB_D + tid;
      float v = (gi < N_NODES * EMB_D) ? nrm[gi] : 0.f;
      s_qf[tid] = v;
      s_qbf[tid] = f32_to_bf16(v);
    }
    if (tid < SROWS) s_cnt[tid] = 0;
    __syncthreads();

    short8 afrag = *(const short8*)&s_qbf[lo5 * EMB_D + hi * 8];
    const f32x16 zacc = (f32x16)0.0f;

    // Pass 1: MFMA approx sims; 5 groups of 4 tiles, loads batched 4-deep.
    float rm[16];
#pragma unroll
    for (int r = 0; r < 16; r++) rm[r] = -INFINITY;
#pragma unroll
    for (int g = 0; g < 5; ++g) {
      int tb = tbase + g * 32 + w * 4;
      int nd[4];
      short8 bf[4];
#pragma unroll
      for (int u = 0; u < 4; u++) {
        nd[u] = (tb + u) * 32 + lo5;
        bf[u] = (short8)(short)0;
        if (nd[u] < N_NODES)
          bf[u] = *(const short8*)&nrmh[(size_t)nd[u] * EMB_D + hi * 8];
      }
#pragma unroll
      for (int u = 0; u < 4; u++) {
        f32x16 acc = __builtin_amdgcn_mfma_f32_32x32x16_bf16(afrag, bf[u], zacc, 0, 0, 0);
        if (nd[u] < N_NODES) {
#pragma unroll
          for (int r = 0; r < 16; r++) rm[r] = fmaxf(rm[r], acc[r]);
        }
      }
    }
#pragma unroll
    for (int r = 0; r < 16; r++) {
      int rl = (r & 3) + 8 * (r >> 2) + 4 * hi;   // C-layout row
      s_smax[rl][w * 32 + lo5] = rm[r];
    }
    __syncthreads();

    // Threshold: fold 256 -> 64 subset maxima, u32 bitonic sort, lane 44.
    for (int q = 0; q < 4; q++) {
      int row = w * 4 + q;
      float m01 = fmaxf(s_smax[row][lane], s_smax[row][64 + lane]);
      float m23 = fmaxf(s_smax[row][128 + lane], s_smax[row][192 + lane]);
      unsigned v = monokey(fmaxf(m01, m23));
#pragma unroll
      for (int k = 2; k <= 64; k <<= 1) {
#pragma unroll
        for (int j = k >> 1; j > 0; j >>= 1) {
          unsigned o = __shfl_xor(v, j);
          bool upper = (lane & j) != 0;
          bool ascend = (lane & k) == 0;
          unsigned mx = v > o ? v : o;
          unsigned mn = v > o ? o : v;
          v = (upper == ascend) ? mx : mn;
        }
      }
      unsigned t20 = __shfl(v, 44);          // 20th largest of 64
      if (lane == 0)
        s_thr[row] = (row0 + row < N_NODES) ? invmono(t20) - GUARD : INFINITY;
    }
    __syncthreads();   // last read of s_smax before overlay reuse

    float thr_r[16];
#pragma unroll
    for (int r = 0; r < 16; r++)
      thr_r[r] = s_thr[(r & 3) + 8 * (r >> 2) + 4 * hi];

    // Pass 2: MFMA rescan; collect u16 ids only.
#pragma unroll
    for (int g = 0; g < 5; ++g) {
      int tb = tbase + g * 32 + w * 4;
      int nd[4];
      short8 bf[4];
#pragma unroll
      for (int u = 0; u < 4; u++) {
        nd[u] = (tb + u) * 32 + lo5;
        bf[u] = (short8)(short)0;
        if (nd[u] < N_NODES)
          bf[u] = *(const short8*)&nrmh[(size_t)nd[u] * EMB_D + hi * 8];
      }
#pragma unroll
      for (int u = 0; u < 4; u++) {
        f32x16 acc = __builtin_amdgcn_mfma_f32_32x32x16_bf16(afrag, bf[u], zacc, 0, 0, 0);
        if (nd[u] < N_NODES) {
#pragma unroll
          for (int r = 0; r < 16; r++) {
            if (acc[r] >= thr_r[r]) {
              int rl = (r & 3) + 8 * (r >> 2) + 4 * hi;
              int slot = atomicAdd(&s_cnt[rl], 1);
              if (slot < CAPM) s_cid[rl][slot] = (unsigned short)nd[u];
            }
          }
        }
      }
    }
    __syncthreads();

    // Exact-dot phase: lane-parallel over candidates.
    for (int q = 0; q < 4; q++) {
      int row = w * 4 + q;
      if (row0 + row >= N_NODES) continue;
      int M = s_cnt[row];
      if (M > CAPM) continue;
      const float4* qp = (const float4*)&s_qf[row * EMB_D];
      float4 qa = qp[0], qb = qp[1], qc = qp[2], qd = qp[3];
      for (int c = lane; c < M; c += 64) {
        int id = s_cid[row][c];
        const float4* pj = (const float4*)(nrm + (size_t)id * EMB_D);
        float sim = dot16q(qa, qb, qc, qd, pj[0], pj[1], pj[2], pj[3]);
        s_ckey[row][c] = ((unsigned long long)monokey(sim) << 32) |
                         (unsigned long long)(0xFFFFFFFFu - (unsigned)id);
      }
    }
    __syncthreads();

    // Rank-by-count per row; wave-serial exact fallback if overflow.
    for (int q = 0; q < 4; q++) {
      int row = w * 4 + q;
      int grow = row0 + row;
      if (grow >= N_NODES) continue;
      unsigned long long* outp = pkeys + ((size_t)grow * JSPLIT + bh) * K_TOP;
      int M = s_cnt[row];
      if (M <= CAPM) {
        for (int c = lane; c < M; c += 64) {
          unsigned long long mykey = s_ckey[row][c];
          int rank = 0;
          for (int i = 0; i < M; i++) rank += (s_ckey[row][i] > mykey) ? 1 : 0;
          if (rank < K_TOP) outp[rank] = mykey;
        }
      } else {
        const float4* qp = (const float4*)&s_qf[row * EMB_D];
        float4 qa = qp[0], qb = qp[1], qc = qp[2], qd = qp[3];
        int j0 = tbase * 32;
        int jend = j0 + HALFT * 32; if (jend > N_NODES) jend = N_NODES;
        unsigned long long prev = ~0ull;
        for (int r = 0; r < K_TOP; r++) {
          unsigned long long best = 0ull;
          for (int j = j0 + lane; j < jend; j += 64) {
            const float4* pj = (const float4*)(nrm + (size_t)j * EMB_D);
            float sim = dot16q(qa, qb, qc, qd, pj[0], pj[1], pj[2], pj[3]);
            unsigned long long key = ((unsigned long long)monokey(sim) << 32) |
                                     (unsigned long long)(0xFFFFFFFFu - (unsigned)j);
            if (key < prev && key > best) best = key;
          }
#pragma unroll
          for (int off = 32; off > 0; off >>= 1) {
            unsigned long long o = __shfl_down(best, off);
            if (o > best) best = o;
          }
          best = __shfl(best, 0);
          prev = best;
          if (lane == 0) outp[r] = best;
        }
      }
    }
  } else {
    // ================= GEMM1 BRANCH (32 rows, 8x2 register blocking) ======
    float (*As)[IN_DIM] = (float(*)[IN_DIM])smem;   // 16 KB
    int r0 = (bid - SIMB) * 32;
    const float4 z4 = {0.f, 0.f, 0.f, 0.f};
    for (int e = tid; e < 32 * (IN_DIM / 4); e += 512) {
      int rr = e >> 5, kk = e & 31;
      int row = r0 + rr;
      ((float4*)&As[rr][0])[kk] =
          (row < N_NODES) ? ((const float4*)(A + (size_t)row * IN_DIM))[kk] : z4;
    }
    __syncthreads();
    int y = tid >> 7;          // 0..3 -> rows y*8..y*8+7
    int c0 = (tid & 127) * 2;  // col pair
    float acc[8][2] = {};
    for (int k4 = 0; k4 < IN_DIM / 4; k4++) {
      float4 a[8];
#pragma unroll
      for (int r = 0; r < 8; r++) a[r] = ((const float4*)&As[y * 8 + r][0])[k4];
      float2 bv[4];
#pragma unroll
      for (int i = 0; i < 4; i++)
        bv[i] = *(const float2*)&B[(size_t)(k4 * 4 + i) * D1 + c0];
#pragma unroll
      for (int r = 0; r < 8; r++) {
        acc[r][0] = fmaf(a[r].x, bv[0].x, acc[r][0]);
        acc[r][1] = fmaf(a[r].x, bv[0].y, acc[r][1]);
        acc[r][0] = fmaf(a[r].y, bv[1].x, acc[r][0]);
        acc[r][1] = fmaf(a[r].y, bv[1].y, acc[r][1]);
        acc[r][0] = fmaf(a[r].z, bv[2].x, acc[r][0]);
        acc[r][1] = fmaf(a[r].z, bv[2].y, acc[r][1]);
        acc[r][0] = fmaf(a[r].w, bv[3].x, acc[r][0]);
        acc[r][1] = fmaf(a[r].w, bv[3].y, acc[r][1]);
      }
    }
#pragma unroll
    for (int r = 0; r < 8; r++) {
      int row = r0 + y * 8 + r;
      if (row < N_NODES) {
        float2 o = {acc[r][0], acc[r][1]};
        *(float2*)&Cc[(size_t)row * D1 + c0] = o;
      }
    }
    // Fused e1: col pair lies in head h = c0>>6; 32-lane group reduce.
    int lane = tid & 63;
    int h = c0 >> 6;
    float as0 = a_src[c0], as1 = a_src[c0 + 1];
    float at0 = a_tgt[c0], at1 = a_tgt[c0 + 1];
#pragma unroll
    for (int r = 0; r < 8; r++) {
      float ps = fmaf(acc[r][1], as1, acc[r][0] * as0);
      float pt = fmaf(acc[r][1], at1, acc[r][0] * at0);
#pragma unroll
      for (int off = 16; off > 0; off >>= 1) {
        ps += __shfl_down(ps, off);
        pt += __shfl_down(pt, off);
      }
      int row = r0 + y * 8 + r;
      if ((lane & 31) == 0 && row < N_NODES) {
        es[(size_t)row * H1 + h] = ps;
        et[(size_t)row * H1 + h] = pt;
      }
    }
  }
}

// Stage B: merge 2x20 exact keys per row -> global top-20 node ids.
__global__ __launch_bounds__(256) void topk_merge(
    const unsigned long long* __restrict__ pkeys, int* __restrict__ topk) {
  __shared__ unsigned long long s_k[4][JSPLIT * K_TOP];
  int w = threadIdx.x >> 6, lane = threadIdx.x & 63;
  int row = blockIdx.x * 4 + w;
  const unsigned long long* src = pkeys + (size_t)row * (JSPLIT * K_TOP);
  if (lane < JSPLIT * K_TOP) s_k[w][lane] = src[lane];
  __syncthreads();
  if (lane < JSPLIT * K_TOP) {
    unsigned long long mykey = s_k[w][lane];
    int rank = 0;
    for (int i = 0; i < JSPLIT * K_TOP; i++)
      rank += (s_k[w][i] > mykey) ? 1 : 0;
    if (rank < K_TOP)
      topk[(size_t)row * K_TOP + rank] =
          (int)(0xFFFFFFFFu - (unsigned)(mykey & 0xFFFFFFFFull));
  }
}

// Fused GAT-1 aggregation + gemm2 + e2 scores. One block = 16 nodes (R10 form).
__global__ __launch_bounds__(256) void agg1_gemm2_kernel(
    const float* __restrict__ h1p, const float* __restrict__ e1s,
    const float* __restrict__ e1t, const int* __restrict__ topk,
    const float* __restrict__ b1, const float* __restrict__ B2,
    const float* __restrict__ a_src, const float* __restrict__ a_tgt,
    float* __restrict__ h2p, float* __restrict__ es, float* __restrict__ et) {
  __shared__ float As[16][D1];          // 16 KB aggregated h1 tile
  __shared__ int nb[16][NEIGH];
  __shared__ float wv[16][NEIGH][H1];
  __shared__ float zz[16][H1];
  int r0 = blockIdx.x * 16;
  int tid = threadIdx.x;

  for (int idx = tid; idx < 16 * NEIGH; idx += 256) {
    int n = idx / NEIGH, jj = idx % NEIGH;
    nb[n][jj] = (jj < K_TOP) ? topk[(size_t)(r0 + n) * K_TOP + jj] : (r0 + n);
  }
  __syncthreads();
  for (int idx = tid; idx < 16 * NEIGH * H1; idx += 256) {
    int e = idx & 3, jj = (idx >> 2) % NEIGH, n = idx / (NEIGH * H1);
    float L = e1s[(size_t)(r0 + n) * H1 + e] + e1t[(size_t)nb[n][jj] * H1 + e];
    wv[n][jj][e] = (L > 0.f) ? L : 0.2f * L;   // leaky_relu 0.2
  }
  __syncthreads();
  if (tid < 16 * H1) {
    int n = tid >> 2, h = tid & 3;
    float m = -INFINITY;
#pragma unroll
    for (int jj = 0; jj < NEIGH; jj++) m = fmaxf(m, wv[n][jj][h]);
    float z = 0.f;
#pragma unroll
    for (int jj = 0; jj < NEIGH; jj++) {
      float wt = expf(wv[n][jj][h] - m);
      z += wt;
      wv[n][jj][h] = wt;
    }
    zz[n][h] = z;
  }
  __syncthreads();
  {
    int h = tid >> 6;
    float bv = b1[tid];
    for (int n = 0; n < 16; n++) {
      float acc = 0.f;
#pragma unroll
      for (int jj = 0; jj < NEIGH; jj++)
        acc = fmaf(wv[n][jj][h], h1p[(size_t)nb[n][jj] * D1 + tid], acc);
      float o = acc / zz[n][h] + bv;
      As[n][tid] = fmaxf(o, 0.f);
    }
  }
  __syncthreads();
  int col = tid & 63, y = tid >> 6;
  float acc4[4] = {0, 0, 0, 0};
  for (int k4 = 0; k4 < D1 / 4; k4++) {
    float4 a[4];
#pragma unroll
    for (int r = 0; r < 4; r++) a[r] = ((const float4*)&As[y * 4 + r][0])[k4];
    float bv[4];
#pragma unroll
    for (int i = 0; i < 4; i++) bv[i] = B2[(size_t)(k4 * 4 + i) * CDIM + col];
#pragma unroll
    for (int r = 0; r < 4; r++) {
      acc4[r] = fmaf(a[r].x, bv[0], acc4[r]);
      acc4[r] = fmaf(a[r].y, bv[1], acc4[r]);
      acc4[r] = fmaf(a[r].z, bv[2], acc4[r]);
      acc4[r] = fmaf(a[r].w, bv[3], acc4[r]);
    }
  }
#pragma unroll
  for (int r = 0; r < 4; r++)
    h2p[(size_t)(r0 + y * 4 + r) * CDIM + col] = acc4[r];
  float as = a_src[col], at = a_tgt[col];
#pragma unroll
  for (int r = 0; r < 4; r++) {
    float ps = acc4[r] * as, pt = acc4[r] * at;
#pragma unroll
    for (int off = 32; off > 0; off >>= 1) {
      ps += __shfl_down(ps, off);
      pt += __shfl_down(pt, off);
    }
    if (col == 0) {
      es[r0 + y * 4 + r] = ps;
      et[r0 + y * 4 + r] = pt;
    }
  }
}

__global__ __launch_bounds__(256) void agg2_kernel(
    const float* __restrict__ h2p, const float* __restrict__ es,
    const float* __restrict__ et, const int* __restrict__ topk,
    const float* __restrict__ b2, float* __restrict__ out) {
  int tid = threadIdx.x;
  int li = tid >> 6;
  int c = tid & 63;
  int i = blockIdx.x * 4 + li;
  __shared__ int nb[4][NEIGH];
  __shared__ float lg[4][NEIGH];
  if (tid < 4 * NEIGH) {
    int li2 = tid / NEIGH, jj = tid % NEIGH;
    int node = blockIdx.x * 4 + li2;
    nb[li2][jj] = (jj < K_TOP) ? topk[(size_t)node * K_TOP + jj] : node;
  }
  __syncthreads();
  if (tid < 4 * NEIGH) {
    int li2 = tid / NEIGH, jj = tid % NEIGH;
    int node = blockIdx.x * 4 + li2;
    float L = es[node] + et[nb[li2][jj]];
    lg[li2][jj] = (L > 0.f) ? L : 0.2f * L;
  }
  __syncthreads();
  float m = -INFINITY;
#pragma unroll
  for (int jj = 0; jj < NEIGH; jj++) m = fmaxf(m, lg[li][jj]);
  float z = 0.f, acc = 0.f;
#pragma unroll
  for (int jj = 0; jj < NEIGH; jj++) {
    float w = expf(lg[li][jj] - m);
    z += w;
    acc = fmaf(w, h2p[(size_t)nb[li][jj] * CDIM + c], acc);
  }
  out[(size_t)i * CDIM + c] = acc / z + b2[c];
}

extern "C" void kernel_launch(void* const* d_in, const int* in_sizes, int n_in,
                              void* d_out, int out_size, void* d_ws, size_t ws_size,
                              hipStream_t stream) {
  const float* x   = (const float*)d_in[0];
  const float* emb = (const float*)d_in[1];
  const float* W1  = (const float*)d_in[2];
  const float* a1s = (const float*)d_in[3];
  const float* a1t = (const float*)d_in[4];
  const float* b1  = (const float*)d_in[5];
  const float* W2  = (const float*)d_in[6];
  const float* a2s = (const float*)d_in[7];
  const float* a2t = (const float*)d_in[8];
  const float* b2  = (const float*)d_in[9];
  float* out = (float*)d_out;

  size_t off = 0;
  auto alloc = [&](size_t bytes) {
    void* p = (char*)d_ws + off;
    off += (bytes + 255) & ~(size_t)255;
    return p;
  };
  float*          nrm  = (float*)alloc((size_t)N_NODES * EMB_D * sizeof(float));
  unsigned short* nrmh = (unsigned short*)alloc((size_t)N_NODES * EMB_D * sizeof(unsigned short));
  int*   topk = (int*)  alloc((size_t)N_NODES * K_TOP * sizeof(int));
  float* h1p  = (float*)alloc((size_t)N_NODES * D1 * sizeof(float));
  float* e1s  = (float*)alloc((size_t)N_NODES * H1 * sizeof(float));
  float* e1t  = (float*)alloc((size_t)N_NODES * H1 * sizeof(float));
  float* h2p  = (float*)alloc((size_t)N_NODES * CDIM * sizeof(float));
  float* e2s  = (float*)alloc((size_t)N_NODES * sizeof(float));
  float* e2t  = (float*)alloc((size_t)N_NODES * sizeof(float));
  // pkeys now lives concurrently with h1p (fat kernel writes both) -> own slot.
  unsigned long long* pkeys =
      (unsigned long long*)alloc((size_t)N_NODES * JSPLIT * K_TOP * sizeof(unsigned long long));
  (void)ws_size; (void)in_sizes; (void)n_in; (void)out_size;

  normalize_kernel<<<(N_NODES + 255) / 256, 256, 0, stream>>>(emb, nrm, nrmh);
  sim_gemm1_fused<<<SIMB + G1B, 512, 0, stream>>>(nrm, nrmh, pkeys,
                                                  x, W1, a1s, a1t, h1p, e1s, e1t);
  topk_merge<<<N_NODES / 4, 256, 0, stream>>>(pkeys, topk);
  agg1_gemm2_kernel<<<N_NODES / 16, 256, 0, stream>>>(h1p, e1s, e1t, topk, b1,
                                                      W2, a2s, a2t, h2p, e2s, e2t);
  agg2_kernel<<<N_NODES / 4, 256, 0, stream>>>(h2p, e2s, e2t, topk, b2, out);
}

// Round 15
// 139.286 us; speedup vs baseline: 1.0673x; 1.0673x over previous
//
#include <hip/hip_runtime.h>
#include <math.h>

// SpatialProcessor: 2-layer GAT over top-K cosine-sim graph. All f32.
// R14 -> R15: best-known composition (fat-kernel fusion reverted -- VGPR
// union 56->128 crushed occupancy 28->20%). sim = R12 form (68.6us,
// reproduced); gemm1 = R13 reg-blocked 8x2/256t; agg1_gemm2 = R10 256t;
// pkeys re-aliased onto h1p (stream-ordered). All exact-path math
// bit-identical to the passing R10-R14 lineage (absmax 4.882812e-4).

#define N_NODES 10000
#define EMB_D   16
#define IN_DIM  128
#define H1      4
#define CDIM    64
#define D1      256   // 4*64
#define K_TOP   20
#define NEIGH   21    // K_TOP + self loop
#define SROWS   32    // rows per sim block
#define NTILES  313   // ceil(10000/32) row-tiles
#define JSPLIT  2
#define HALFT   160   // j-tiles per half (padded 320/2)
#define CAPM    96    // candidate capacity per row (per half)
#define GUARD   0.016f // 2 * bf16 dot error bound (2^-7)

typedef __attribute__((ext_vector_type(8)))  short short8;   // 8 bf16
typedef __attribute__((ext_vector_type(16))) float f32x16;

__device__ __forceinline__ unsigned monokey(float v) {
  unsigned u = __float_as_uint(v);
  return (u & 0x80000000u) ? ~u : (u | 0x80000000u);
}
__device__ __forceinline__ float invmono(unsigned m) {
  unsigned u = (m & 0x80000000u) ? (m ^ 0x80000000u) : ~m;
  return __uint_as_float(u);
}
__device__ __forceinline__ unsigned short f32_to_bf16(float f) {
  unsigned u = __float_as_uint(f);
  unsigned r = 0x7FFFu + ((u >> 16) & 1u);
  return (unsigned short)((u + r) >> 16);
}

// Fixed-order fmaf dot; MUST be bit-identical at every call site.
__device__ __forceinline__ float dot16q(float4 qa, float4 qb, float4 qc, float4 qd,
                                        float4 v0, float4 v1, float4 v2, float4 v3) {
  float a = 0.f;
  a = fmaf(qa.x, v0.x, a); a = fmaf(qa.y, v0.y, a);
  a = fmaf(qa.z, v0.z, a); a = fmaf(qa.w, v0.w, a);
  a = fmaf(qb.x, v1.x, a); a = fmaf(qb.y, v1.y, a);
  a = fmaf(qb.z, v1.z, a); a = fmaf(qb.w, v1.w, a);
  a = fmaf(qc.x, v2.x, a); a = fmaf(qc.y, v2.y, a);
  a = fmaf(qc.z, v2.z, a); a = fmaf(qc.w, v2.w, a);
  a = fmaf(qd.x, v3.x, a); a = fmaf(qd.y, v3.y, a);
  a = fmaf(qd.z, v3.z, a); a = fmaf(qd.w, v3.w, a);
  return a;
}

__global__ __launch_bounds__(256) void normalize_kernel(
    const float* __restrict__ emb, float* __restrict__ nrm,
    unsigned short* __restrict__ nrmh) {
  int i = blockIdx.x * 256 + threadIdx.x;
  if (i >= N_NODES) return;
  const float4* p = (const float4*)(emb + (size_t)i * EMB_D);
  float4 v[4];
  float ss = 0.f;
#pragma unroll
  for (int k = 0; k < 4; k++) {
    v[k] = p[k];
    ss = fmaf(v[k].x, v[k].x, ss);
    ss = fmaf(v[k].y, v[k].y, ss);
    ss = fmaf(v[k].z, v[k].z, ss);
    ss = fmaf(v[k].w, v[k].w, ss);
  }
  float nv = sqrtf(ss);
  float4* o = (float4*)(nrm + (size_t)i * EMB_D);
  ushort4* oh = (ushort4*)(nrmh + (size_t)i * EMB_D);
#pragma unroll
  for (int k = 0; k < 4; k++) {
    float4 t;
    t.x = v[k].x / nv; t.y = v[k].y / nv; t.z = v[k].z / nv; t.w = v[k].w / nv;
    o[k] = t;
    ushort4 h;
    h.x = f32_to_bf16(t.x); h.y = f32_to_bf16(t.y);
    h.z = f32_to_bf16(t.z); h.w = f32_to_bf16(t.w);
    oh[k] = h;
  }
}

// Stage A: grid (NTILES, JSPLIT); 32 rows x one j-half per 512-thread block.
__global__ __launch_bounds__(512) void sim_topk_part(
    const float* __restrict__ nrm, const unsigned short* __restrict__ nrmh,
    unsigned long long* __restrict__ pkeys) {
  __shared__ unsigned short s_qbf[SROWS * EMB_D];        // 1 KB
  __shared__ float s_qf[SROWS * EMB_D];                  // 2 KB
  // 32 KB overlay: s_smax (pass1/threshold), then s_cid+s_ckey (pass2+).
  __shared__ __align__(16) char s_ovl[32768];
  float (*s_smax)[256] = (float(*)[256])s_ovl;                      // 32 KB
  unsigned long long (*s_ckey)[CAPM] = (unsigned long long(*)[CAPM])s_ovl;  // 24 KB
  unsigned short (*s_cid)[CAPM] =
      (unsigned short(*)[CAPM])(s_ovl + 24576);                     // 6 KB
  __shared__ float s_thr[SROWS];
  __shared__ int s_cnt[SROWS];

  int tid = threadIdx.x;
  int w = tid >> 6, lane = tid & 63;
  int lo5 = lane & 31, hi = lane >> 5;
  int row0 = blockIdx.x * SROWS;
  int bh = blockIdx.y;
  int tbase = bh * HALFT;

  if (tid < SROWS * EMB_D) {
    int gi = row0 * EMB_D + tid;
    float v = (gi < N_NODES * EMB_D) ? nrm[gi] : 0.f;
    s_qf[tid] = v;
    s_qbf[tid] = f32_to_bf16(v);
  }
  if (tid < SROWS) s_cnt[tid] = 0;
  __syncthreads();

  short8 afrag = *(const short8*)&s_qbf[lo5 * EMB_D + hi * 8];
  const f32x16 zacc = (f32x16)0.0f;

  // ---- Pass 1: MFMA approx sims; 5 groups of 4 tiles, loads batched 4-deep
  float rm[16];
#pragma unroll
  for (int r = 0; r < 16; r++) rm[r] = -INFINITY;

#pragma unroll
  for (int g = 0; g < 5; ++g) {
    int tb = tbase + g * 32 + w * 4;
    int nd[4];
    short8 bf[4];
#pragma unroll
    for (int u = 0; u < 4; u++) {
      nd[u] = (tb + u) * 32 + lo5;
      bf[u] = (short8)(short)0;
      if (nd[u] < N_NODES)
        bf[u] = *(const short8*)&nrmh[(size_t)nd[u] * EMB_D + hi * 8];
    }
#pragma unroll
    for (int u = 0; u < 4; u++) {
      f32x16 acc = __builtin_amdgcn_mfma_f32_32x32x16_bf16(afrag, bf[u], zacc, 0, 0, 0);
      if (nd[u] < N_NODES) {
#pragma unroll
        for (int r = 0; r < 16; r++) rm[r] = fmaxf(rm[r], acc[r]);
      }
    }
  }
#pragma unroll
  for (int r = 0; r < 16; r++) {
    int rl = (r & 3) + 8 * (r >> 2) + 4 * hi;   // C-layout row
    s_smax[rl][w * 32 + lo5] = rm[r];
  }
  __syncthreads();

  // ---- Threshold: fold 256 -> 64 subset maxima, u32 bitonic sort, lane 44 ----
  for (int q = 0; q < 4; q++) {
    int row = w * 4 + q;
    float m01 = fmaxf(s_smax[row][lane], s_smax[row][64 + lane]);
    float m23 = fmaxf(s_smax[row][128 + lane], s_smax[row][192 + lane]);
    unsigned v = monokey(fmaxf(m01, m23));
#pragma unroll
    for (int k = 2; k <= 64; k <<= 1) {
#pragma unroll
      for (int j = k >> 1; j > 0; j >>= 1) {
        unsigned o = __shfl_xor(v, j);
        bool upper = (lane & j) != 0;
        bool ascend = (lane & k) == 0;
        unsigned mx = v > o ? v : o;
        unsigned mn = v > o ? o : v;
        v = (upper == ascend) ? mx : mn;   // ascending overall: lane63 = max
      }
    }
    unsigned t20 = __shfl(v, 44);          // 20th largest of 64
    if (lane == 0)
      s_thr[row] = (row0 + row < N_NODES) ? invmono(t20) - GUARD : INFINITY;
  }
  __syncthreads();   // last read of s_smax before overlay reuse

  float thr_r[16];
#pragma unroll
  for (int r = 0; r < 16; r++)
    thr_r[r] = s_thr[(r & 3) + 8 * (r >> 2) + 4 * hi];

  // ---- Pass 2: MFMA rescan; collect u16 ids only ----
#pragma unroll
  for (int g = 0; g < 5; ++g) {
    int tb = tbase + g * 32 + w * 4;
    int nd[4];
    short8 bf[4];
#pragma unroll
    for (int u = 0; u < 4; u++) {
      nd[u] = (tb + u) * 32 + lo5;
      bf[u] = (short8)(short)0;
      if (nd[u] < N_NODES)
        bf[u] = *(const short8*)&nrmh[(size_t)nd[u] * EMB_D + hi * 8];
    }
#pragma unroll
    for (int u = 0; u < 4; u++) {
      f32x16 acc = __builtin_amdgcn_mfma_f32_32x32x16_bf16(afrag, bf[u], zacc, 0, 0, 0);
      if (nd[u] < N_NODES) {
#pragma unroll
        for (int r = 0; r < 16; r++) {
          if (acc[r] >= thr_r[r]) {
            int rl = (r & 3) + 8 * (r >> 2) + 4 * hi;
            int slot = atomicAdd(&s_cnt[rl], 1);
            if (slot < CAPM) s_cid[rl][slot] = (unsigned short)nd[u];
          }
        }
      }
    }
  }
  __syncthreads();

  // ---- Exact-dot phase: lane-parallel over candidates ----
  for (int q = 0; q < 4; q++) {
    int row = w * 4 + q;
    if (row0 + row >= N_NODES) continue;
    int M = s_cnt[row];
    if (M > CAPM) continue;
    const float4* qp = (const float4*)&s_qf[row * EMB_D];
    float4 qa = qp[0], qb = qp[1], qc = qp[2], qd = qp[3];
    for (int c = lane; c < M; c += 64) {
      int id = s_cid[row][c];
      const float4* pj = (const float4*)(nrm + (size_t)id * EMB_D);
      float sim = dot16q(qa, qb, qc, qd, pj[0], pj[1], pj[2], pj[3]);
      s_ckey[row][c] = ((unsigned long long)monokey(sim) << 32) |
                       (unsigned long long)(0xFFFFFFFFu - (unsigned)id);
    }
  }
  __syncthreads();

  // ---- Rank-by-count per row; wave-serial exact fallback if overflow ----
  for (int q = 0; q < 4; q++) {
    int row = w * 4 + q;
    int grow = row0 + row;
    if (grow >= N_NODES) continue;
    unsigned long long* outp = pkeys + ((size_t)grow * JSPLIT + bh) * K_TOP;
    int M = s_cnt[row];
    if (M <= CAPM) {
      for (int c = lane; c < M; c += 64) {
        unsigned long long mykey = s_ckey[row][c];
        int rank = 0;
        for (int i = 0; i < M; i++) rank += (s_ckey[row][i] > mykey) ? 1 : 0;
        if (rank < K_TOP) outp[rank] = mykey;
      }
    } else {
      const float4* qp = (const float4*)&s_qf[row * EMB_D];
      float4 qa = qp[0], qb = qp[1], qc = qp[2], qd = qp[3];
      int j0 = tbase * 32;
      int jend = j0 + HALFT * 32; if (jend > N_NODES) jend = N_NODES;
      unsigned long long prev = ~0ull;
      for (int r = 0; r < K_TOP; r++) {
        unsigned long long best = 0ull;
        for (int j = j0 + lane; j < jend; j += 64) {
          const float4* pj = (const float4*)(nrm + (size_t)j * EMB_D);
          float sim = dot16q(qa, qb, qc, qd, pj[0], pj[1], pj[2], pj[3]);
          unsigned long long key = ((unsigned long long)monokey(sim) << 32) |
                                   (unsigned long long)(0xFFFFFFFFu - (unsigned)j);
          if (key < prev && key > best) best = key;
        }
#pragma unroll
        for (int off = 32; off > 0; off >>= 1) {
          unsigned long long o = __shfl_down(best, off);
          if (o > best) best = o;
        }
        best = __shfl(best, 0);
        prev = best;
        if (lane == 0) outp[r] = best;
      }
    }
  }
}

// Stage B: merge 2x20 exact keys per row -> global top-20 node ids.
__global__ __launch_bounds__(256) void topk_merge(
    const unsigned long long* __restrict__ pkeys, int* __restrict__ topk) {
  __shared__ unsigned long long s_k[4][JSPLIT * K_TOP];
  int w = threadIdx.x >> 6, lane = threadIdx.x & 63;
  int row = blockIdx.x * 4 + w;
  const unsigned long long* src = pkeys + (size_t)row * (JSPLIT * K_TOP);
  if (lane < JSPLIT * K_TOP) s_k[w][lane] = src[lane];
  __syncthreads();
  if (lane < JSPLIT * K_TOP) {
    unsigned long long mykey = s_k[w][lane];
    int rank = 0;
    for (int i = 0; i < JSPLIT * K_TOP; i++)
      rank += (s_k[w][i] > mykey) ? 1 : 0;
    if (rank < K_TOP)
      topk[(size_t)row * K_TOP + rank] =
          (int)(0xFFFFFFFFu - (unsigned)(mykey & 0xFFFFFFFFull));
  }
}

// C[10000,256] = A[10000,128] @ B[128,256], fused e1 scores.
// Register blocking 8 rows x 2 cols per thread; 256 threads / 16-row tile.
__global__ __launch_bounds__(256) void gemm1_kernel(
    const float* __restrict__ A, const float* __restrict__ B,
    const float* __restrict__ a_src, const float* __restrict__ a_tgt,
    float* __restrict__ Cc, float* __restrict__ es, float* __restrict__ et) {
  __shared__ float As[16][IN_DIM];   // 8 KB
  int r0 = blockIdx.x * 16;
  int tid = threadIdx.x;
  {
    int rr = tid >> 4;       // 16 threads per row, 2 float4 each
    int kk = tid & 15;
    ((float4*)&As[rr][0])[kk] = ((const float4*)(A + (size_t)(r0 + rr) * IN_DIM))[kk];
    ((float4*)&As[rr][0])[kk + 16] =
        ((const float4*)(A + (size_t)(r0 + rr) * IN_DIM))[kk + 16];
  }
  __syncthreads();
  int y = tid >> 7;          // 0..1 -> rows y*8..y*8+7
  int c0 = (tid & 127) * 2;  // col pair
  float acc[8][2] = {};
  for (int k4 = 0; k4 < IN_DIM / 4; k4++) {
    float4 a[8];
#pragma unroll
    for (int r = 0; r < 8; r++) a[r] = ((const float4*)&As[y * 8 + r][0])[k4];
    float2 bv[4];
#pragma unroll
    for (int i = 0; i < 4; i++)
      bv[i] = *(const float2*)&B[(size_t)(k4 * 4 + i) * D1 + c0];
#pragma unroll
    for (int r = 0; r < 8; r++) {
      acc[r][0] = fmaf(a[r].x, bv[0].x, acc[r][0]);
      acc[r][1] = fmaf(a[r].x, bv[0].y, acc[r][1]);
      acc[r][0] = fmaf(a[r].y, bv[1].x, acc[r][0]);
      acc[r][1] = fmaf(a[r].y, bv[1].y, acc[r][1]);
      acc[r][0] = fmaf(a[r].z, bv[2].x, acc[r][0]);
      acc[r][1] = fmaf(a[r].z, bv[2].y, acc[r][1]);
      acc[r][0] = fmaf(a[r].w, bv[3].x, acc[r][0]);
      acc[r][1] = fmaf(a[r].w, bv[3].y, acc[r][1]);
    }
  }
#pragma unroll
  for (int r = 0; r < 8; r++) {
    float2 o = {acc[r][0], acc[r][1]};
    *(float2*)&Cc[(size_t)(r0 + y * 8 + r) * D1 + c0] = o;
  }
  // Fused e1: lane pair covers cols c0,c0+1 (same head); 32-lane group = head.
  int lane = tid & 63;
  int h = c0 >> 6;
  float as0 = a_src[c0], as1 = a_src[c0 + 1];
  float at0 = a_tgt[c0], at1 = a_tgt[c0 + 1];
#pragma unroll
  for (int r = 0; r < 8; r++) {
    float ps = fmaf(acc[r][1], as1, acc[r][0] * as0);
    float pt = fmaf(acc[r][1], at1, acc[r][0] * at0);
#pragma unroll
    for (int off = 16; off > 0; off >>= 1) {
      ps += __shfl_down(ps, off);
      pt += __shfl_down(pt, off);
    }
    if ((lane & 31) == 0) {
      es[(size_t)(r0 + y * 8 + r) * H1 + h] = ps;
      et[(size_t)(r0 + y * 8 + r) * H1 + h] = pt;
    }
  }
}

// Fused GAT-1 aggregation + gemm2 + e2 scores. One block = 16 nodes (R10 form).
__global__ __launch_bounds__(256) void agg1_gemm2_kernel(
    const float* __restrict__ h1p, const float* __restrict__ e1s,
    const float* __restrict__ e1t, const int* __restrict__ topk,
    const float* __restrict__ b1, const float* __restrict__ B2,
    const float* __restrict__ a_src, const float* __restrict__ a_tgt,
    float* __restrict__ h2p, float* __restrict__ es, float* __restrict__ et) {
  __shared__ float As[16][D1];          // 16 KB aggregated h1 tile
  __shared__ int nb[16][NEIGH];
  __shared__ float wv[16][NEIGH][H1];
  __shared__ float zz[16][H1];
  int r0 = blockIdx.x * 16;
  int tid = threadIdx.x;

  for (int idx = tid; idx < 16 * NEIGH; idx += 256) {
    int n = idx / NEIGH, jj = idx % NEIGH;
    nb[n][jj] = (jj < K_TOP) ? topk[(size_t)(r0 + n) * K_TOP + jj] : (r0 + n);
  }
  __syncthreads();
  for (int idx = tid; idx < 16 * NEIGH * H1; idx += 256) {
    int e = idx & 3, jj = (idx >> 2) % NEIGH, n = idx / (NEIGH * H1);
    float L = e1s[(size_t)(r0 + n) * H1 + e] + e1t[(size_t)nb[n][jj] * H1 + e];
    wv[n][jj][e] = (L > 0.f) ? L : 0.2f * L;   // leaky_relu 0.2
  }
  __syncthreads();
  if (tid < 16 * H1) {
    int n = tid >> 2, h = tid & 3;
    float m = -INFINITY;
#pragma unroll
    for (int jj = 0; jj < NEIGH; jj++) m = fmaxf(m, wv[n][jj][h]);
    float z = 0.f;
#pragma unroll
    for (int jj = 0; jj < NEIGH; jj++) {
      float wt = expf(wv[n][jj][h] - m);
      z += wt;
      wv[n][jj][h] = wt;
    }
    zz[n][h] = z;
  }
  __syncthreads();
  {
    int h = tid >> 6;
    float bv = b1[tid];
    for (int n = 0; n < 16; n++) {
      float acc = 0.f;
#pragma unroll
      for (int jj = 0; jj < NEIGH; jj++)
        acc = fmaf(wv[n][jj][h], h1p[(size_t)nb[n][jj] * D1 + tid], acc);
      float o = acc / zz[n][h] + bv;
      As[n][tid] = fmaxf(o, 0.f);
    }
  }
  __syncthreads();
  int col = tid & 63, y = tid >> 6;
  float acc4[4] = {0, 0, 0, 0};
  for (int k4 = 0; k4 < D1 / 4; k4++) {
    float4 a[4];
#pragma unroll
    for (int r = 0; r < 4; r++) a[r] = ((const float4*)&As[y * 4 + r][0])[k4];
    float bv[4];
#pragma unroll
    for (int i = 0; i < 4; i++) bv[i] = B2[(size_t)(k4 * 4 + i) * CDIM + col];
#pragma unroll
    for (int r = 0; r < 4; r++) {
      acc4[r] = fmaf(a[r].x, bv[0], acc4[r]);
      acc4[r] = fmaf(a[r].y, bv[1], acc4[r]);
      acc4[r] = fmaf(a[r].z, bv[2], acc4[r]);
      acc4[r] = fmaf(a[r].w, bv[3], acc4[r]);
    }
  }
#pragma unroll
  for (int r = 0; r < 4; r++)
    h2p[(size_t)(r0 + y * 4 + r) * CDIM + col] = acc4[r];
  float as = a_src[col], at = a_tgt[col];
#pragma unroll
  for (int r = 0; r < 4; r++) {
    float ps = acc4[r] * as, pt = acc4[r] * at;
#pragma unroll
    for (int off = 32; off > 0; off >>= 1) {
      ps += __shfl_down(ps, off);
      pt += __shfl_down(pt, off);
    }
    if (col == 0) {
      es[r0 + y * 4 + r] = ps;
      et[r0 + y * 4 + r] = pt;
    }
  }
}

__global__ __launch_bounds__(256) void agg2_kernel(
    const float* __restrict__ h2p, const float* __restrict__ es,
    const float* __restrict__ et, const int* __restrict__ topk,
    const float* __restrict__ b2, float* __restrict__ out) {
  int tid = threadIdx.x;
  int li = tid >> 6;
  int c = tid & 63;
  int i = blockIdx.x * 4 + li;
  __shared__ int nb[4][NEIGH];
  __shared__ float lg[4][NEIGH];
  if (tid < 4 * NEIGH) {
    int li2 = tid / NEIGH, jj = tid % NEIGH;
    int node = blockIdx.x * 4 + li2;
    nb[li2][jj] = (jj < K_TOP) ? topk[(size_t)node * K_TOP + jj] : node;
  }
  __syncthreads();
  if (tid < 4 * NEIGH) {
    int li2 = tid / NEIGH, jj = tid % NEIGH;
    int node = blockIdx.x * 4 + li2;
    float L = es[node] + et[nb[li2][jj]];
    lg[li2][jj] = (L > 0.f) ? L : 0.2f * L;
  }
  __syncthreads();
  float m = -INFINITY;
#pragma unroll
  for (int jj = 0; jj < NEIGH; jj++) m = fmaxf(m, lg[li][jj]);
  float z = 0.f, acc = 0.f;
#pragma unroll
  for (int jj = 0; jj < NEIGH; jj++) {
    float w = expf(lg[li][jj] - m);
    z += w;
    acc = fmaf(w, h2p[(size_t)nb[li][jj] * CDIM + c], acc);
  }
  out[(size_t)i * CDIM + c] = acc / z + b2[c];
}

extern "C" void kernel_launch(void* const* d_in, const int* in_sizes, int n_in,
                              void* d_out, int out_size, void* d_ws, size_t ws_size,
                              hipStream_t stream) {
  const float* x   = (const float*)d_in[0];
  const float* emb = (const float*)d_in[1];
  const float* W1  = (const float*)d_in[2];
  const float* a1s = (const float*)d_in[3];
  const float* a1t = (const float*)d_in[4];
  const float* b1  = (const float*)d_in[5];
  const float* W2  = (const float*)d_in[6];
  const float* a2s = (const float*)d_in[7];
  const float* a2t = (const float*)d_in[8];
  const float* b2  = (const float*)d_in[9];
  float* out = (float*)d_out;

  size_t off = 0;
  auto alloc = [&](size_t bytes) {
    void* p = (char*)d_ws + off;
    off += (bytes + 255) & ~(size_t)255;
    return p;
  };
  float*          nrm  = (float*)alloc((size_t)N_NODES * EMB_D * sizeof(float));
  unsigned short* nrmh = (unsigned short*)alloc((size_t)N_NODES * EMB_D * sizeof(unsigned short));
  int*   topk = (int*)  alloc((size_t)N_NODES * K_TOP * sizeof(int));
  float* h1p  = (float*)alloc((size_t)N_NODES * D1 * sizeof(float));
  float* e1s  = (float*)alloc((size_t)N_NODES * H1 * sizeof(float));
  float* e1t  = (float*)alloc((size_t)N_NODES * H1 * sizeof(float));
  float* h2p  = (float*)alloc((size_t)N_NODES * CDIM * sizeof(float));
  float* e2s  = (float*)alloc((size_t)N_NODES * sizeof(float));
  float* e2t  = (float*)alloc((size_t)N_NODES * sizeof(float));
  // pkeys (3.2MB) aliases h1p (10.24MB): consumed by topk_merge before
  // gemm1 writes h1p (stream-ordered).
  unsigned long long* pkeys = (unsigned long long*)h1p;
  (void)ws_size; (void)in_sizes; (void)n_in; (void)out_size;

  normalize_kernel<<<(N_NODES + 255) / 256, 256, 0, stream>>>(emb, nrm, nrmh);
  sim_topk_part<<<dim3(NTILES, JSPLIT), 512, 0, stream>>>(nrm, nrmh, pkeys);
  topk_merge<<<N_NODES / 4, 256, 0, stream>>>(pkeys, topk);
  gemm1_kernel<<<N_NODES / 16, 256, 0, stream>>>(x, W1, a1s, a1t, h1p, e1s, e1t);
  agg1_gemm2_kernel<<<N_NODES / 16, 256, 0, stream>>>(h1p, e1s, e1t, topk, b1,
                                                      W2, a2s, a2t, h2p, e2s, e2t);
  agg2_kernel<<<N_NODES / 4, 256, 0, stream>>>(h2p, e2s, e2t, topk, b2, out);
}